// Round 1
// baseline (461.555 us; speedup 1.0000x reference)
//
#include <hip/hip_runtime.h>
#include <hip/hip_fp16.h>

typedef _Float16 f16;
typedef __attribute__((ext_vector_type(8))) _Float16 f16x8;
typedef __attribute__((ext_vector_type(4))) _Float16 f16x4;
typedef __attribute__((ext_vector_type(4))) float f32x4;

#define BM 128
#define BN 128
#define BK 64

__device__ __forceinline__ void gll16(const void* src, void* dst) {
  __builtin_amdgcn_global_load_lds((const __attribute__((address_space(1))) void*)src,
                                   (__attribute__((address_space(3))) void*)dst,
                                   16, 0, 0);
}

// C[m,n] = sum_k A[m,k] * B[n,k]  ("BT" form; both operands row-major along K)
// MODE 0: store C fp16
// MODE 1: p = exp(acc*scale + mask[row,col]); store fp16 P; row-sum partials -> lvec (32 slots/row)
// MODE 2: store C fp32 = acc * (1 / lvec[z*M + row])
template<int MODE>
__global__ __launch_bounds__(256, 2)
void gemm_bt(const f16* __restrict__ Aall, const f16* __restrict__ Ball,
             void* __restrict__ Call,
             int M, int N, int K, int lda, int ldb, int ldc,
             long strideA, long strideB, long strideC,
             const float* __restrict__ maskAll, long strideMask,
             float* __restrict__ lvec, float scale)
{
  __shared__ f16 smA[2][BM * BK];
  __shared__ f16 smB[2][BN * BK];

  const int z = blockIdx.z;
  const f16* A = Aall + (long)z * strideA;
  const f16* B = Ball + (long)z * strideB;

  const int tid  = threadIdx.x;
  const int wid  = tid >> 6;
  const int lane = tid & 63;
  const int wm = wid >> 1;
  const int wn = wid & 1;

  const long brow = (long)blockIdx.y * BM;
  const long bcol = (long)blockIdx.x * BN;

  f32x4 acc[4][4] = {};

  const int lr = lane & 15;

  const int nt = K / BK;

  // Stage one 128x64 fp16 tile of A and of B into LDS.
  // LDS layout: linear row-major [128][64], chunk c (16B) at byte c*16; row=c>>3, slot=c&7.
  // XOR swizzle: LDS slot s of row r holds global slot s^(r&7)  (source pre-swizzled,
  // dest linear — required by global_load_lds; reads apply the same XOR).
  auto stage = [&](int buf, int t) {
    const int kb = t * BK;
    #pragma unroll
    for (int i = 0; i < 4; ++i) {
      int cb  = wid * 256 + i * 64;      // wave-uniform chunk base
      int c   = cb + lane;
      int row = c >> 3;
      int sl  = (c & 7) ^ (row & 7);
      gll16(A + (brow + row) * lda + kb + sl * 8, &smA[buf][cb * 8]);
    }
    #pragma unroll
    for (int i = 0; i < 4; ++i) {
      int cb  = wid * 256 + i * 64;
      int c   = cb + lane;
      int row = c >> 3;
      int sl  = (c & 7) ^ (row & 7);
      gll16(B + (bcol + row) * ldb + kb + sl * 8, &smB[buf][cb * 8]);
    }
  };

  stage(0, 0);
  __syncthreads();   // compiler drains vmcnt before s_barrier

  for (int t = 0; t < nt; ++t) {
    const int cur = t & 1;
    if (t + 1 < nt) stage(cur ^ 1, t + 1);   // prefetch next tile (drained at loop-end barrier)
    #pragma unroll
    for (int ks = 0; ks < 2; ++ks) {
      f16x8 af[4], bf[4];
      #pragma unroll
      for (int m = 0; m < 4; ++m) {
        int row  = wm * 64 + m * 16 + lr;
        int slot = (ks * 4 + (lane >> 4)) ^ (row & 7);
        af[m] = *(const f16x8*)((const char*)smA[cur] + row * (BK * 2) + slot * 16);
      }
      #pragma unroll
      for (int n = 0; n < 4; ++n) {
        int row  = wn * 64 + n * 16 + lr;
        int slot = (ks * 4 + (lane >> 4)) ^ (row & 7);
        bf[n] = *(const f16x8*)((const char*)smB[cur] + row * (BK * 2) + slot * 16);
      }
      #pragma unroll
      for (int m = 0; m < 4; ++m)
        #pragma unroll
        for (int n = 0; n < 4; ++n)
          acc[m][n] = __builtin_amdgcn_mfma_f32_16x16x32_f16(af[m], bf[n], acc[m][n], 0, 0, 0);
    }
    __syncthreads();
  }

  // C/D layout (m89-verified, dtype-independent): col = lane&15, row = (lane>>4)*4 + reg
  const int rb = (lane >> 4) * 4;

  if (MODE == 0) {
    f16* C = (f16*)Call + (long)z * strideC;
    #pragma unroll
    for (int m = 0; m < 4; ++m)
      #pragma unroll
      for (int j = 0; j < 4; ++j) {
        long grow = brow + wm * 64 + m * 16 + rb + j;
        #pragma unroll
        for (int n = 0; n < 4; ++n) {
          long gcol = bcol + wn * 64 + n * 16 + lr;
          C[grow * ldc + gcol] = (f16)acc[m][n][j];
        }
      }
  } else if (MODE == 1) {
    f16* C = (f16*)Call + (long)z * strideC;
    const float* mask = maskAll + (long)z * strideMask;
    #pragma unroll
    for (int m = 0; m < 4; ++m)
      #pragma unroll
      for (int j = 0; j < 4; ++j) {
        long grow = brow + wm * 64 + m * 16 + rb + j;
        float s = 0.f;
        #pragma unroll
        for (int n = 0; n < 4; ++n) {
          long gcol = bcol + wn * 64 + n * 16 + lr;
          float p = __expf(acc[m][n][j] * scale + mask[grow * ldc + gcol]);
          C[grow * ldc + gcol] = (f16)p;
          s += p;
        }
        // row-sum over the 16 lanes holding this row's 16 cols (per n-frag already summed)
        s += __shfl_xor(s, 1);
        s += __shfl_xor(s, 2);
        s += __shfl_xor(s, 4);
        s += __shfl_xor(s, 8);
        if (lr == 0)
          lvec[((long)z * M + grow) * 32 + blockIdx.x * 2 + wn] = s;
      }
  } else {
    float* C = (float*)Call + (long)z * strideC;
    #pragma unroll
    for (int m = 0; m < 4; ++m)
      #pragma unroll
      for (int j = 0; j < 4; ++j) {
        long grow = brow + wm * 64 + m * 16 + rb + j;
        float inv = 1.0f / lvec[(long)z * M + grow];
        #pragma unroll
        for (int n = 0; n < 4; ++n) {
          long gcol = bcol + wn * 64 + n * 16 + lr;
          C[grow * ldc + gcol] = acc[m][n][j] * inv;
        }
      }
  }
}

__global__ void cvt_f32_to_f16(const float* __restrict__ src, f16* __restrict__ dst, int n4) {
  int i = blockIdx.x * blockDim.x + threadIdx.x;
  if (i < n4) {
    float4 vv = ((const float4*)src)[i];
    f16x4 o;
    o[0] = (f16)vv.x; o[1] = (f16)vv.y; o[2] = (f16)vv.z; o[3] = (f16)vv.w;
    ((f16x4*)dst)[i] = o;
  }
}

__global__ void reduce_l(const float* __restrict__ lpart, float* __restrict__ lsum, int n) {
  int i = blockIdx.x * blockDim.x + threadIdx.x;
  if (i < n) {
    float s = 0.f;
    #pragma unroll
    for (int j = 0; j < 32; ++j) s += lpart[(long)i * 32 + j];
    lsum[i] = s;
  }
}

extern "C" void kernel_launch(void* const* d_in, const int* in_sizes, int n_in,
                              void* d_out, int out_size, void* d_ws, size_t ws_size,
                              hipStream_t stream)
{
  const int Bb = 8, L = 2048, J = 2048, D = 1024, H = 1024;
  const float* q    = (const float*)d_in[0];
  const float* k    = (const float*)d_in[1];
  const float* v    = (const float*)d_in[2];
  const float* mask = (const float*)d_in[3];
  const float* Wq   = (const float*)d_in[4];
  const float* Wk   = (const float*)d_in[5];
  const float* Wv   = (const float*)d_in[6];
  float* out = (float*)d_out;
  char*  ws  = (char*)d_ws;

  // workspace layout (bytes); q/k/v fp16 region is dead after projections -> reused for P
  f16* qf  = (f16*)(ws + 0);            // 32 MB
  f16* kf  = (f16*)(ws + 33554432);     // 32 MB
  f16* vf  = (f16*)(ws + 67108864);     // 32 MB
  f16* Pm  = (f16*)(ws + 0);            // 64 MB (reuse of qf/kf/vf region)
  f16* Wqf = (f16*)(ws + 100663296);    // 2 MB
  f16* Wkf = (f16*)(ws + 102760448);
  f16* Wvf = (f16*)(ws + 104857600);
  f16* qp  = (f16*)(ws + 106954752);    // 32 MB
  f16* kp  = (f16*)(ws + 140509184);    // 32 MB
  f16* vpT = (f16*)(ws + 174063616);    // 32 MB  (stored H x J, i.e. transposed)
  float* lpart = (float*)(ws + 207618048); // 2 MB
  float* lsum  = (float*)(ws + 209715200); // 64 KB

  const long nQ = (long)Bb * L * D;  // 16,777,216
  const long nW = (long)H * D;       //  1,048,576

  // 1) fp32 -> fp16 converts
  cvt_f32_to_f16<<<dim3((unsigned)(nQ / 4 / 256)), dim3(256), 0, stream>>>(q, qf, (int)(nQ / 4));
  cvt_f32_to_f16<<<dim3((unsigned)(nQ / 4 / 256)), dim3(256), 0, stream>>>(k, kf, (int)(nQ / 4));
  cvt_f32_to_f16<<<dim3((unsigned)(nQ / 4 / 256)), dim3(256), 0, stream>>>(v, vf, (int)(nQ / 4));
  cvt_f32_to_f16<<<dim3((unsigned)(nW / 4 / 256)), dim3(256), 0, stream>>>(Wq, Wqf, (int)(nW / 4));
  cvt_f32_to_f16<<<dim3((unsigned)(nW / 4 / 256)), dim3(256), 0, stream>>>(Wk, Wkf, (int)(nW / 4));
  cvt_f32_to_f16<<<dim3((unsigned)(nW / 4 / 256)), dim3(256), 0, stream>>>(Wv, Wvf, (int)(nW / 4));

  // 2) projections
  // qp[bl,h] = sum_d q[bl,d] * Wq[h,d]     M=16384 N=1024 K=1024
  gemm_bt<0><<<dim3(1024 / BN, 16384 / BM, 1), dim3(256), 0, stream>>>(
      qf, Wqf, qp, 16384, 1024, 1024, 1024, 1024, 1024,
      0, 0, 0, nullptr, 0, nullptr, 0.f);
  // kp[bj,h] = sum_d k[bj,d] * Wk[h,d]
  gemm_bt<0><<<dim3(1024 / BN, 16384 / BM, 1), dim3(256), 0, stream>>>(
      kf, Wkf, kp, 16384, 1024, 1024, 1024, 1024, 1024,
      0, 0, 0, nullptr, 0, nullptr, 0.f);
  // vpT[b][h,j] = sum_d Wv[h,d] * v[b][j,d]   M=1024 N=2048 K=1024, batched over b
  gemm_bt<0><<<dim3(2048 / BN, 1024 / BM, 8), dim3(256), 0, stream>>>(
      Wvf, vf, vpT, 1024, 2048, 1024, 1024, 1024, 2048,
      0, (long)J * D, (long)H * J, nullptr, 0, nullptr, 0.f);

  // 3) P[b][l,j] = exp(qp.kp^T / 32 + mask), fp16, + row-sum partials
  gemm_bt<1><<<dim3(2048 / BN, 2048 / BM, 8), dim3(256), 0, stream>>>(
      qp, kp, Pm, 2048, 2048, 1024, 1024, 1024, 2048,
      (long)L * H, (long)J * H, (long)L * J, mask, (long)L * J, lpart, 0.03125f);

  reduce_l<<<dim3(16384 / 256), dim3(256), 0, stream>>>(lpart, lsum, 16384);

  // 4) out[b][l,h] = (sum_j P[l,j] * vpT[h,j]) / l[b,l]   M=2048 N=1024 K=2048
  gemm_bt<2><<<dim3(1024 / BN, 2048 / BM, 8), dim3(256), 0, stream>>>(
      Pm, vpT, out, 2048, 1024, 2048, 2048, 2048, 1024,
      (long)L * J, (long)H * J, (long)L * H, nullptr, 0, lsum, 0.f);
}

// Round 2
// 411.605 us; speedup vs baseline: 1.1214x; 1.1214x over previous
//
#include <hip/hip_runtime.h>
#include <hip/hip_fp16.h>

typedef _Float16 f16;
typedef __attribute__((ext_vector_type(8))) _Float16 f16x8;
typedef __attribute__((ext_vector_type(4))) _Float16 f16x4;
typedef __attribute__((ext_vector_type(4))) float f32x4;

#define BM 256
#define BN 256
#define BK 32

__device__ __forceinline__ void gll16(const void* src, void* dst) {
  __builtin_amdgcn_global_load_lds((const __attribute__((address_space(1))) void*)src,
                                   (__attribute__((address_space(3))) void*)dst,
                                   16, 0, 0);
}

// C[m,n] = sum_k A[m,k] * B[n,k]  ("BT" form; both operands row-major along K)
// 256x256 tile, BK=32, 512 threads (8 waves, 2M x 4N), 3-buffer LDS rotation with
// counted vmcnt (T3+T4): while computing tile kt from buf[kt%3], stage tile kt+2
// into buf[(kt+2)%3] (vacated at end of tile kt-1: all its ds_reads RETURNED data
// before tile kt's stage issues — lgkmcnt(0) precedes the barrier). Boundary wait
// vmcnt(4) keeps tile kt+2's 4 loads in flight; never drains to 0 in the loop.
// MODE 0: store C fp16
// MODE 1: p = exp(acc*scale + mask[row,col]); store fp16 P; row-sum partials -> lvec (32/row)
// MODE 2: store C fp32 = acc * (1 / lvec[z*M + row])
template<int MODE>
__global__ __launch_bounds__(512, 2)
void gemm_bt(const f16* __restrict__ Aall, const f16* __restrict__ Ball,
             void* __restrict__ Call,
             int M, int N, int K, int lda, int ldb, int ldc,
             long strideA, long strideB, long strideC,
             const float* __restrict__ maskAll, long strideMask,
             float* __restrict__ lvec, float scale)
{
  __shared__ f16 smA[3][BM * BK];   // 3 x 16 KB
  __shared__ f16 smB[3][BN * BK];   // 3 x 16 KB   -> 96 KiB total

  const int z = blockIdx.z;
  const f16* A = Aall + (long)z * strideA;
  const f16* B = Ball + (long)z * strideB;

  const int tid  = threadIdx.x;
  const int wid  = tid >> 6;
  const int lane = tid & 63;
  const int wm = wid >> 2;        // 0..1 -> 128 rows of C each
  const int wn = wid & 3;         // 0..3 -> 64 cols of C each
  const int lr = lane & 15;
  const int g  = lane >> 4;       // k-slot 0..3
  // swizzle const: row = 16*k + lr  =>  (row&3)^((row>>2)&3) == (lr&3)^((lr>>2)&3)
  const int xc = (lr & 3) ^ ((lr >> 2) & 3);

  const long brow = (long)blockIdx.y * BM;
  const long bcol = (long)blockIdx.x * BN;
  const int  nt   = K / BK;

  f32x4 acc[8][4] = {};

  // Stage one 256x32 f16 operand tile (16 KB = 1024 x 16B chunks, 2 chunks/thread).
  // LDS linear (gll requirement); source pre-swizzled: linear slot s holds global
  // slot s ^ (row&3) ^ ((row>>2)&3)  (involution; 2-way-max bank pattern on read).
  auto stageA = [&](int buf, int t) {
    #pragma unroll
    for (int i = 0; i < 2; ++i) {
      int c   = i * 512 + tid;
      int row = c >> 2;
      int sl  = (c & 3) ^ ((row & 3) ^ ((row >> 2) & 3));
      gll16(A + (brow + row) * (long)lda + t * BK + sl * 8, &smA[buf][c * 8]);
    }
  };
  auto stageB = [&](int buf, int t) {
    #pragma unroll
    for (int i = 0; i < 2; ++i) {
      int c   = i * 512 + tid;
      int row = c >> 2;
      int sl  = (c & 3) ^ ((row & 3) ^ ((row >> 2) & 3));
      gll16(B + (bcol + row) * (long)ldb + t * BK + sl * 8, &smB[buf][c * 8]);
    }
  };

  // prologue: tiles 0 and 1 fully staged; wait for tile 0 (tile 1 stays in flight)
  stageA(0, 0); stageB(0, 0);
  stageA(1, 1); stageB(1, 1);
  asm volatile("s_waitcnt vmcnt(4)" ::: "memory");
  __builtin_amdgcn_s_barrier();

  int buf = 0;
  for (int kt = 0; kt < nt; ++kt) {
    int bufn = buf + 2; if (bufn >= 3) bufn -= 3;
    const f16* sa = &smA[buf][0];
    const f16* sb = &smB[buf][0];

    // ---- phase 0: B frags + A frags (m 0..3), stage A of kt+2, MFMA quadrant 0
    f16x8 af[4], bf[4];
    #pragma unroll
    for (int n = 0; n < 4; ++n) {
      int row = wn * 64 + n * 16 + lr;
      bf[n] = *(const f16x8*)(sb + row * BK + (g ^ xc) * 8);
    }
    #pragma unroll
    for (int m = 0; m < 4; ++m) {
      int row = wm * 128 + m * 16 + lr;
      af[m] = *(const f16x8*)(sa + row * BK + (g ^ xc) * 8);
    }
    if (kt + 2 < nt) stageA(bufn, kt + 2);
    __builtin_amdgcn_s_barrier();
    asm volatile("s_waitcnt lgkmcnt(0)" ::: "memory");
    __builtin_amdgcn_sched_barrier(0);
    __builtin_amdgcn_s_setprio(1);
    #pragma unroll
    for (int m = 0; m < 4; ++m)
      #pragma unroll
      for (int n = 0; n < 4; ++n)
        acc[m][n] = __builtin_amdgcn_mfma_f32_16x16x32_f16(af[m], bf[n], acc[m][n], 0, 0, 0);
    __builtin_amdgcn_s_setprio(0);
    __builtin_amdgcn_s_barrier();

    // ---- phase 1: A frags (m 4..7), stage B of kt+2, MFMA quadrant 1
    #pragma unroll
    for (int m = 0; m < 4; ++m) {
      int row = wm * 128 + 64 + m * 16 + lr;
      af[m] = *(const f16x8*)(sa + row * BK + (g ^ xc) * 8);
    }
    if (kt + 2 < nt) stageB(bufn, kt + 2);
    __builtin_amdgcn_s_barrier();
    asm volatile("s_waitcnt lgkmcnt(0)" ::: "memory");
    __builtin_amdgcn_sched_barrier(0);
    __builtin_amdgcn_s_setprio(1);
    #pragma unroll
    for (int m = 0; m < 4; ++m)
      #pragma unroll
      for (int n = 0; n < 4; ++n)
        acc[m + 4][n] = __builtin_amdgcn_mfma_f32_16x16x32_f16(af[m], bf[n], acc[m + 4][n], 0, 0, 0);
    __builtin_amdgcn_s_setprio(0);
    __builtin_amdgcn_sched_barrier(0);
    // tile boundary: ensure tile kt+1 landed; keep kt+2's 4 loads in flight
    if (kt + 2 < nt) { asm volatile("s_waitcnt vmcnt(4)" ::: "memory"); }
    else             { asm volatile("s_waitcnt vmcnt(0)" ::: "memory"); }
    __builtin_amdgcn_s_barrier();
    buf = buf + 1 == 3 ? 0 : buf + 1;
  }

  // C/D layout (m89-verified): col = lane&15, row = (lane>>4)*4 + reg
  const int rb = (lane >> 4) * 4;

  if (MODE == 0) {
    f16* C = (f16*)Call + (long)z * strideC;
    #pragma unroll
    for (int m = 0; m < 8; ++m)
      #pragma unroll
      for (int j = 0; j < 4; ++j) {
        long grow = brow + wm * 128 + m * 16 + rb + j;
        #pragma unroll
        for (int n = 0; n < 4; ++n) {
          long gcol = bcol + wn * 64 + n * 16 + lr;
          C[grow * ldc + gcol] = (f16)acc[m][n][j];
        }
      }
  } else if (MODE == 1) {
    f16* C = (f16*)Call + (long)z * strideC;
    const float* mask = maskAll + (long)z * strideMask;
    #pragma unroll
    for (int m = 0; m < 8; ++m)
      #pragma unroll
      for (int j = 0; j < 4; ++j) {
        long grow = brow + wm * 128 + m * 16 + rb + j;
        float s = 0.f;
        #pragma unroll
        for (int n = 0; n < 4; ++n) {
          long gcol = bcol + wn * 64 + n * 16 + lr;
          float p = __expf(acc[m][n][j] * scale + mask[grow * ldc + gcol]);
          C[grow * ldc + gcol] = (f16)p;
          s += p;
        }
        s += __shfl_xor(s, 1);
        s += __shfl_xor(s, 2);
        s += __shfl_xor(s, 4);
        s += __shfl_xor(s, 8);
        if (lr == 0)
          lvec[((long)z * M + grow) * 32 + blockIdx.x * 4 + wn] = s;
      }
  } else {
    float* C = (float*)Call + (long)z * strideC;
    #pragma unroll
    for (int m = 0; m < 8; ++m)
      #pragma unroll
      for (int j = 0; j < 4; ++j) {
        long grow = brow + wm * 128 + m * 16 + rb + j;
        float inv = 1.0f / lvec[(long)z * M + grow];
        #pragma unroll
        for (int n = 0; n < 4; ++n) {
          long gcol = bcol + wn * 64 + n * 16 + lr;
          C[grow * ldc + gcol] = acc[m][n][j] * inv;
        }
      }
  }
}

__global__ void cvt_f32_to_f16(const float* __restrict__ src, f16* __restrict__ dst, int n4) {
  int i = blockIdx.x * blockDim.x + threadIdx.x;
  if (i < n4) {
    float4 vv = ((const float4*)src)[i];
    f16x4 o;
    o[0] = (f16)vv.x; o[1] = (f16)vv.y; o[2] = (f16)vv.z; o[3] = (f16)vv.w;
    ((f16x4*)dst)[i] = o;
  }
}

__global__ void reduce_l(const float* __restrict__ lpart, float* __restrict__ lsum, int n) {
  int i = blockIdx.x * blockDim.x + threadIdx.x;
  if (i < n) {
    float s = 0.f;
    #pragma unroll
    for (int j = 0; j < 32; ++j) s += lpart[(long)i * 32 + j];
    lsum[i] = s;
  }
}

extern "C" void kernel_launch(void* const* d_in, const int* in_sizes, int n_in,
                              void* d_out, int out_size, void* d_ws, size_t ws_size,
                              hipStream_t stream)
{
  const int Bb = 8, L = 2048, J = 2048, D = 1024, H = 1024;
  const float* q    = (const float*)d_in[0];
  const float* k    = (const float*)d_in[1];
  const float* v    = (const float*)d_in[2];
  const float* mask = (const float*)d_in[3];
  const float* Wq   = (const float*)d_in[4];
  const float* Wk   = (const float*)d_in[5];
  const float* Wv   = (const float*)d_in[6];
  float* out = (float*)d_out;
  char*  ws  = (char*)d_ws;

  // workspace layout (bytes); q/k/v fp16 region is dead after projections -> reused for P
  f16* qf  = (f16*)(ws + 0);            // 32 MB
  f16* kf  = (f16*)(ws + 33554432);     // 32 MB
  f16* vf  = (f16*)(ws + 67108864);     // 32 MB
  f16* Pm  = (f16*)(ws + 0);            // 64 MB (reuse of qf/kf/vf region)
  f16* Wqf = (f16*)(ws + 100663296);    // 2 MB
  f16* Wkf = (f16*)(ws + 102760448);
  f16* Wvf = (f16*)(ws + 104857600);
  f16* qp  = (f16*)(ws + 106954752);    // 32 MB
  f16* kp  = (f16*)(ws + 140509184);    // 32 MB
  f16* vpT = (f16*)(ws + 174063616);    // 32 MB  (stored H x J, i.e. transposed)
  float* lpart = (float*)(ws + 207618048); // 2 MB
  float* lsum  = (float*)(ws + 209715200); // 64 KB

  const long nQ = (long)Bb * L * D;  // 16,777,216
  const long nW = (long)H * D;       //  1,048,576

  // 1) fp32 -> fp16 converts
  cvt_f32_to_f16<<<dim3((unsigned)(nQ / 4 / 256)), dim3(256), 0, stream>>>(q, qf, (int)(nQ / 4));
  cvt_f32_to_f16<<<dim3((unsigned)(nQ / 4 / 256)), dim3(256), 0, stream>>>(k, kf, (int)(nQ / 4));
  cvt_f32_to_f16<<<dim3((unsigned)(nQ / 4 / 256)), dim3(256), 0, stream>>>(v, vf, (int)(nQ / 4));
  cvt_f32_to_f16<<<dim3((unsigned)(nW / 4 / 256)), dim3(256), 0, stream>>>(Wq, Wqf, (int)(nW / 4));
  cvt_f32_to_f16<<<dim3((unsigned)(nW / 4 / 256)), dim3(256), 0, stream>>>(Wk, Wkf, (int)(nW / 4));
  cvt_f32_to_f16<<<dim3((unsigned)(nW / 4 / 256)), dim3(256), 0, stream>>>(Wv, Wvf, (int)(nW / 4));

  // 2) projections
  // qp[bl,h] = sum_d q[bl,d] * Wq[h,d]     M=16384 N=1024 K=1024
  gemm_bt<0><<<dim3(1024 / BN, 16384 / BM, 1), dim3(512), 0, stream>>>(
      qf, Wqf, qp, 16384, 1024, 1024, 1024, 1024, 1024,
      0, 0, 0, nullptr, 0, nullptr, 0.f);
  // kp[bj,h] = sum_d k[bj,d] * Wk[h,d]
  gemm_bt<0><<<dim3(1024 / BN, 16384 / BM, 1), dim3(512), 0, stream>>>(
      kf, Wkf, kp, 16384, 1024, 1024, 1024, 1024, 1024,
      0, 0, 0, nullptr, 0, nullptr, 0.f);
  // vpT[b][h,j] = sum_d Wv[h,d] * v[b][j,d]   M=1024 N=2048 K=1024, batched over b
  gemm_bt<0><<<dim3(2048 / BN, 1024 / BM, 8), dim3(512), 0, stream>>>(
      Wvf, vf, vpT, 1024, 2048, 1024, 1024, 1024, 2048,
      0, (long)J * D, (long)H * J, nullptr, 0, nullptr, 0.f);

  // 3) P[b][l,j] = exp(qp.kp^T / 32 + mask), fp16, + row-sum partials
  gemm_bt<1><<<dim3(2048 / BN, 2048 / BM, 8), dim3(512), 0, stream>>>(
      qp, kp, Pm, 2048, 2048, 1024, 1024, 1024, 2048,
      (long)L * H, (long)J * H, (long)L * J, mask, (long)L * J, lpart, 0.03125f);

  reduce_l<<<dim3(16384 / 256), dim3(256), 0, stream>>>(lpart, lsum, 16384);

  // 4) out[b][l,h] = (sum_j P[l,j] * vpT[h,j]) / l[b,l]   M=2048 N=1024 K=2048
  gemm_bt<2><<<dim3(1024 / BN, 2048 / BM, 8), dim3(512), 0, stream>>>(
      Pm, vpT, out, 2048, 1024, 2048, 2048, 2048, 1024,
      (long)L * J, (long)H * J, (long)L * H, nullptr, 0, lsum, 0.f);
}

// Round 3
// 380.550 us; speedup vs baseline: 1.2129x; 1.0816x over previous
//
#include <hip/hip_runtime.h>
#include <hip/hip_fp16.h>

typedef _Float16 f16;
typedef __attribute__((ext_vector_type(8))) _Float16 f16x8;
typedef __attribute__((ext_vector_type(4))) _Float16 f16x4;
typedef __attribute__((ext_vector_type(4))) float f32x4;

#define BM 256
#define BN 256
#define BK 64

__device__ __forceinline__ void gll16(const void* src, void* dst) {
  __builtin_amdgcn_global_load_lds((const __attribute__((address_space(1))) void*)src,
                                   (__attribute__((address_space(3))) void*)dst,
                                   16, 0, 0);
}

// C[m,n] = sum_k A[m,k] * B[n,k]  ("BT" form; both operands row-major along K)
// m201-style schedule: 256x256 tile, BK=64, 512 thr (8 waves 2Mx4N), double-buffered
// LDS (128 KiB), 4 phases per K-tile, 16 MFMA/phase, half-tile gll staging in
// ph0 (A) / ph1 (B), boundary vmcnt(0) (newest load >=2 phases old => ~free).
// Swizzle: linear slot s of row r holds global slot s^(r&7)  (BK=64: row*128B drops
// out of bank index; 8-slot spread => 0 conflicts, measured in R1).
// MODE 0: store C fp16
// MODE 1: p = exp(acc*scale + mask[row,col]); store fp16 P; row-sum partials -> lvec (32/row)
// MODE 2: store C fp32 = acc * (1 / lvec[z*M + row])
template<int MODE>
__global__ __launch_bounds__(512, 2)
void gemm_bt(const f16* __restrict__ Aall, const f16* __restrict__ Ball,
             void* __restrict__ Call,
             int M, int N, int K, int lda, int ldb, int ldc,
             long strideA, long strideB, long strideC,
             const float* __restrict__ maskAll, long strideMask,
             float* __restrict__ lvec, float scale)
{
  __shared__ __align__(16) f16 smA[2][BM * BK];   // 2 x 32 KB
  __shared__ __align__(16) f16 smB[2][BN * BK];   // 2 x 32 KB  -> 128 KiB

  const int z = blockIdx.z;
  const f16* A = Aall + (long)z * strideA;
  const f16* B = Ball + (long)z * strideB;

  const int tid  = threadIdx.x;
  const int wid  = tid >> 6;
  const int lane = tid & 63;
  const int wm = wid >> 2;        // 0..1 -> 128 rows of C
  const int wn = wid & 3;         // 0..3 -> 64 cols of C
  const int lr = lane & 15;
  const int g  = lane >> 4;       // k-slot 0..3

  const long brow = (long)blockIdx.y * BM;
  const long bcol = (long)blockIdx.x * BN;
  const int  nt   = K / BK;

  f32x4 acc[8][4] = {};

  // Stage 2 chunks (16B each) of a 256x64 f16 tile; chunk c: row=c>>3, linear slot=c&7,
  // global slot = (c&7)^(row&7). gll dest linear: wave-uniform base + lane*16.
  auto stA = [&](int buf, int t, int i0) {
    #pragma unroll
    for (int ii = 0; ii < 2; ++ii) {
      int c   = (i0 + ii) * 512 + tid;
      int row = c >> 3;
      int sl  = (c & 7) ^ (row & 7);
      gll16(A + (brow + row) * (long)lda + t * BK + sl * 8, &smA[buf][c * 8]);
    }
  };
  auto stB = [&](int buf, int t, int i0) {
    #pragma unroll
    for (int ii = 0; ii < 2; ++ii) {
      int c   = (i0 + ii) * 512 + tid;
      int row = c >> 3;
      int sl  = (c & 7) ^ (row & 7);
      gll16(B + (bcol + row) * (long)ldb + t * BK + sl * 8, &smB[buf][c * 8]);
    }
  };
  // fragment read: row r, K-half ks (0/1): global slot = ks*4+g, linear = ^(r&7)
  auto ld = [&](const f16* base, int r, int ks) -> f16x8 {
    return *(const f16x8*)(base + r * BK + (((ks << 2) + g) ^ (r & 7)) * 8);
  };

  // prologue: full tile 0
  stA(0, 0, 0); stA(0, 0, 2); stB(0, 0, 0); stB(0, 0, 2);
  asm volatile("s_waitcnt vmcnt(0)" ::: "memory");
  __builtin_amdgcn_s_barrier();

  for (int kt = 0; kt < nt; ++kt) {
    const int cur = kt & 1;
    const f16* sa = smA[cur];
    const f16* sb = smB[cur];
    const bool pf = (kt + 1 < nt);
    f16x8 af[4], bf[4];

    // ---- ph0: bf ks0 + af(m0-3) ks0 ; stage next A ; MFMA q0
    #pragma unroll
    for (int n = 0; n < 4; ++n) bf[n] = ld(sb, wn * 64 + n * 16 + lr, 0);
    #pragma unroll
    for (int m = 0; m < 4; ++m) af[m] = ld(sa, wm * 128 + m * 16 + lr, 0);
    if (pf) { stA(cur ^ 1, kt + 1, 0); stA(cur ^ 1, kt + 1, 2); }
    __builtin_amdgcn_s_barrier();
    asm volatile("s_waitcnt lgkmcnt(0)" ::: "memory");
    __builtin_amdgcn_sched_barrier(0);
    __builtin_amdgcn_s_setprio(1);
    #pragma unroll
    for (int m = 0; m < 4; ++m)
      #pragma unroll
      for (int n = 0; n < 4; ++n)
        acc[m][n] = __builtin_amdgcn_mfma_f32_16x16x32_f16(af[m], bf[n], acc[m][n], 0, 0, 0);
    __builtin_amdgcn_s_setprio(0);
    __builtin_amdgcn_s_barrier();

    // ---- ph1: af(m4-7) ks0 ; stage next B ; MFMA q1
    #pragma unroll
    for (int m = 0; m < 4; ++m) af[m] = ld(sa, wm * 128 + 64 + m * 16 + lr, 0);
    if (pf) { stB(cur ^ 1, kt + 1, 0); stB(cur ^ 1, kt + 1, 2); }
    __builtin_amdgcn_s_barrier();
    asm volatile("s_waitcnt lgkmcnt(0)" ::: "memory");
    __builtin_amdgcn_sched_barrier(0);
    __builtin_amdgcn_s_setprio(1);
    #pragma unroll
    for (int m = 0; m < 4; ++m)
      #pragma unroll
      for (int n = 0; n < 4; ++n)
        acc[m + 4][n] = __builtin_amdgcn_mfma_f32_16x16x32_f16(af[m], bf[n], acc[m + 4][n], 0, 0, 0);
    __builtin_amdgcn_s_setprio(0);
    __builtin_amdgcn_s_barrier();

    // ---- ph2: bf ks1 + af(m0-3) ks1 ; MFMA q2
    #pragma unroll
    for (int n = 0; n < 4; ++n) bf[n] = ld(sb, wn * 64 + n * 16 + lr, 1);
    #pragma unroll
    for (int m = 0; m < 4; ++m) af[m] = ld(sa, wm * 128 + m * 16 + lr, 1);
    __builtin_amdgcn_s_barrier();
    asm volatile("s_waitcnt lgkmcnt(0)" ::: "memory");
    __builtin_amdgcn_sched_barrier(0);
    __builtin_amdgcn_s_setprio(1);
    #pragma unroll
    for (int m = 0; m < 4; ++m)
      #pragma unroll
      for (int n = 0; n < 4; ++n)
        acc[m][n] = __builtin_amdgcn_mfma_f32_16x16x32_f16(af[m], bf[n], acc[m][n], 0, 0, 0);
    __builtin_amdgcn_s_setprio(0);
    __builtin_amdgcn_s_barrier();

    // ---- ph3: af(m4-7) ks1 ; MFMA q3 ; boundary
    #pragma unroll
    for (int m = 0; m < 4; ++m) af[m] = ld(sa, wm * 128 + 64 + m * 16 + lr, 1);
    __builtin_amdgcn_s_barrier();
    asm volatile("s_waitcnt lgkmcnt(0)" ::: "memory");
    __builtin_amdgcn_sched_barrier(0);
    __builtin_amdgcn_s_setprio(1);
    #pragma unroll
    for (int m = 0; m < 4; ++m)
      #pragma unroll
      for (int n = 0; n < 4; ++n)
        acc[m + 4][n] = __builtin_amdgcn_mfma_f32_16x16x32_f16(af[m], bf[n], acc[m + 4][n], 0, 0, 0);
    __builtin_amdgcn_s_setprio(0);
    __builtin_amdgcn_sched_barrier(0);
    asm volatile("s_waitcnt vmcnt(0)" ::: "memory");   // next tile fully landed (loads >=2 phases old)
    __builtin_amdgcn_s_barrier();
  }

  // C/D layout (m89-verified): col = lane&15, row = (lane>>4)*4 + reg
  const int rb = (lane >> 4) * 4;

  if (MODE == 0) {
    f16* C = (f16*)Call + (long)z * strideC;
    #pragma unroll
    for (int m = 0; m < 8; ++m)
      #pragma unroll
      for (int j = 0; j < 4; ++j) {
        long grow = brow + wm * 128 + m * 16 + rb + j;
        #pragma unroll
        for (int n = 0; n < 4; ++n) {
          long gcol = bcol + wn * 64 + n * 16 + lr;
          C[grow * ldc + gcol] = (f16)acc[m][n][j];
        }
      }
  } else if (MODE == 1) {
    f16* C = (f16*)Call + (long)z * strideC;
    const float* mask = maskAll + (long)z * strideMask;
    #pragma unroll
    for (int m = 0; m < 8; ++m)
      #pragma unroll
      for (int j = 0; j < 4; ++j) {
        long grow = brow + wm * 128 + m * 16 + rb + j;
        float s = 0.f;
        #pragma unroll
        for (int n = 0; n < 4; ++n) {
          long gcol = bcol + wn * 64 + n * 16 + lr;
          float p = __expf(acc[m][n][j] * scale + mask[grow * ldc + gcol]);
          C[grow * ldc + gcol] = (f16)p;
          s += p;
        }
        s += __shfl_xor(s, 1);
        s += __shfl_xor(s, 2);
        s += __shfl_xor(s, 4);
        s += __shfl_xor(s, 8);
        if (lr == 0)
          lvec[((long)z * M + grow) * 32 + blockIdx.x * 4 + wn] = s;
      }
  } else {
    float* C = (float*)Call + (long)z * strideC;
    #pragma unroll
    for (int m = 0; m < 8; ++m)
      #pragma unroll
      for (int j = 0; j < 4; ++j) {
        long grow = brow + wm * 128 + m * 16 + rb + j;
        float inv = 1.0f / lvec[(long)z * M + grow];
        #pragma unroll
        for (int n = 0; n < 4; ++n) {
          long gcol = bcol + wn * 64 + n * 16 + lr;
          C[grow * ldc + gcol] = acc[m][n][j] * inv;
        }
      }
  }
}

// one grid-strided kernel converting q,k,v,Wq,Wk,Wv fp32 -> fp16
__global__ void cvt_all(const float* __restrict__ q, const float* __restrict__ k,
                        const float* __restrict__ v, const float* __restrict__ Wq,
                        const float* __restrict__ Wk, const float* __restrict__ Wv,
                        f16* __restrict__ qf, f16* __restrict__ kf, f16* __restrict__ vf,
                        f16* __restrict__ Wqf, f16* __restrict__ Wkf, f16* __restrict__ Wvf)
{
  const long NQ4 = 4194304, NW4 = 262144;       // float4 counts
  const long total = 3 * NQ4 + 3 * NW4;         // 13,107,200
  for (long i = (long)blockIdx.x * blockDim.x + threadIdx.x; i < total;
       i += (long)gridDim.x * blockDim.x) {
    const float* src; f16* dst; long j = i;
    if      (j <     NQ4)           { src = q;  dst = qf; }
    else if (j < 2 * NQ4)           { src = k;  dst = kf;  j -= NQ4; }
    else if (j < 3 * NQ4)           { src = v;  dst = vf;  j -= 2 * NQ4; }
    else if (j < 3 * NQ4 + NW4)     { src = Wq; dst = Wqf; j -= 3 * NQ4; }
    else if (j < 3 * NQ4 + 2 * NW4) { src = Wk; dst = Wkf; j -= 3 * NQ4 + NW4; }
    else                            { src = Wv; dst = Wvf; j -= 3 * NQ4 + 2 * NW4; }
    float4 vv = ((const float4*)src)[j];
    f16x4 o;
    o[0] = (f16)vv.x; o[1] = (f16)vv.y; o[2] = (f16)vv.z; o[3] = (f16)vv.w;
    ((f16x4*)dst)[j] = o;
  }
}

__global__ void reduce_l(const float* __restrict__ lpart, float* __restrict__ lsum, int n) {
  int i = blockIdx.x * blockDim.x + threadIdx.x;
  if (i < n) {
    float s = 0.f;
    #pragma unroll
    for (int j = 0; j < 32; ++j) s += lpart[(long)i * 32 + j];
    lsum[i] = s;
  }
}

extern "C" void kernel_launch(void* const* d_in, const int* in_sizes, int n_in,
                              void* d_out, int out_size, void* d_ws, size_t ws_size,
                              hipStream_t stream)
{
  const float* q    = (const float*)d_in[0];
  const float* k    = (const float*)d_in[1];
  const float* v    = (const float*)d_in[2];
  const float* mask = (const float*)d_in[3];
  const float* Wq   = (const float*)d_in[4];
  const float* Wk   = (const float*)d_in[5];
  const float* Wv   = (const float*)d_in[6];
  float* out = (float*)d_out;
  char*  ws  = (char*)d_ws;

  // workspace layout (bytes); q/k/v fp16 region is dead after projections -> reused for P
  f16* qf  = (f16*)(ws + 0);            // 32 MB
  f16* kf  = (f16*)(ws + 33554432);     // 32 MB
  f16* vf  = (f16*)(ws + 67108864);     // 32 MB
  f16* Pm  = (f16*)(ws + 0);            // 64 MB (reuse of qf/kf/vf region)
  f16* Wqf = (f16*)(ws + 100663296);    // 2 MB
  f16* Wkf = (f16*)(ws + 102760448);
  f16* Wvf = (f16*)(ws + 104857600);
  f16* qp  = (f16*)(ws + 106954752);    // 32 MB
  f16* kp  = (f16*)(ws + 140509184);    // 32 MB
  f16* vpT = (f16*)(ws + 174063616);    // 32 MB  (stored H x J, i.e. transposed)
  float* lpart = (float*)(ws + 207618048); // 2 MB
  float* lsum  = (float*)(ws + 209715200); // 64 KB

  const long L = 2048, J = 2048, D = 1024, H = 1024;

  // 1) fp32 -> fp16 converts (single launch)
  cvt_all<<<dim3(2048), dim3(256), 0, stream>>>(q, k, v, Wq, Wk, Wv, qf, kf, vf, Wqf, Wkf, Wvf);

  // 2) projections
  // qp[bl,h] = sum_d q[bl,d] * Wq[h,d]     M=16384 N=1024 K=1024
  gemm_bt<0><<<dim3(1024 / BN, 16384 / BM, 1), dim3(512), 0, stream>>>(
      qf, Wqf, qp, 16384, 1024, 1024, 1024, 1024, 1024,
      0, 0, 0, nullptr, 0, nullptr, 0.f);
  // kp[bj,h] = sum_d k[bj,d] * Wk[h,d]
  gemm_bt<0><<<dim3(1024 / BN, 16384 / BM, 1), dim3(512), 0, stream>>>(
      kf, Wkf, kp, 16384, 1024, 1024, 1024, 1024, 1024,
      0, 0, 0, nullptr, 0, nullptr, 0.f);
  // vpT[b][h,j] = sum_d Wv[h,d] * v[b][j,d]   M=1024 N=2048 K=1024, batched over b
  gemm_bt<0><<<dim3(2048 / BN, 1024 / BM, 8), dim3(512), 0, stream>>>(
      Wvf, vf, vpT, 1024, 2048, 1024, 1024, 1024, 2048,
      0, J * D, H * J, nullptr, 0, nullptr, 0.f);

  // 3) P[b][l,j] = exp(qp.kp^T / 32 + mask), fp16, + row-sum partials
  gemm_bt<1><<<dim3(2048 / BN, 2048 / BM, 8), dim3(512), 0, stream>>>(
      qp, kp, Pm, 2048, 2048, 1024, 1024, 1024, 2048,
      L * H, J * H, L * J, mask, L * J, lpart, 0.03125f);

  reduce_l<<<dim3(16384 / 256), dim3(256), 0, stream>>>(lpart, lsum, 16384);

  // 4) out[b][l,h] = (sum_j P[l,j] * vpT[h,j]) / l[b,l]   M=2048 N=1024 K=2048
  gemm_bt<2><<<dim3(1024 / BN, 2048 / BM, 8), dim3(512), 0, stream>>>(
      Pm, vpT, out, 2048, 1024, 2048, 2048, 2048, 1024,
      L * J, H * J, L * H, nullptr, 0, lsum, 0.f);
}